// Round 13
// baseline (243.274 us; speedup 1.0000x reference)
//
#include <hip/hip_runtime.h>
#include <hip/hip_bf16.h>
#include <math.h>

#define GAMMA 0.05f
#define NP2 64          // 8192/128 panels
#define SYM2 2080       // NP2*(NP2+1)/2
#define NBLK 8256       // 2*SYM2 + NP2*NP2

typedef __attribute__((ext_vector_type(8))) short bf16x8;
typedef __attribute__((ext_vector_type(4))) float f32x4;

static __device__ __forceinline__ unsigned f32_to_bf16(float x) {
    unsigned u = __float_as_uint(x);
    u += 0x7fffu + ((u >> 16) & 1u);   // RNE
    return u >> 16;
}

static __device__ __forceinline__ void gload_lds16(const void* g, void* l) {
    __builtin_amdgcn_global_load_lds(
        (const __attribute__((address_space(1))) void*)g,
        (__attribute__((address_space(3))) void*)l, 16, 0, 0);
}

// ws layout (bytes):
//   0       : 3 doubles: acc[0]=xx_off, acc[1]=yy_off, acc[2]=xy
//   64      : unsigned counter (blocks-done)
//   1024    : float ENw[8192] = W[i]*exp(-g*||N_i||^2)
//   33792   : float ER [8192] =      exp(-g*||R_i||^2)
//   66560   : bf16 Nsw[8192][128], row-major 256B rows, intra-row swizzle
//   2163712 : bf16 Rsw same
// Intra-row swizzle: byte ^= (row&7)<<4 -> conflict-free ds_read_b128 when
// 16 lanes read 16 consecutive rows at one 16B column.

__global__ __launch_bounds__(256) void prep_kernel(
    const float* __restrict__ Nmat, const float* __restrict__ Rmat,
    const float* __restrict__ W,
    float* __restrict__ ENw, float* __restrict__ ER,
    unsigned short* __restrict__ Nsw, unsigned short* __restrict__ Rsw,
    unsigned* __restrict__ zero_region, int nblkN)
{
    // zero the accumulators + counter (68 B) once; prep precedes mmd in-stream
    if (blockIdx.x == 0 && threadIdx.x < 17) zero_region[threadIdx.x] = 0u;

    const int isR  = (blockIdx.x >= nblkN) ? 1 : 0;
    const int bloc = blockIdx.x - isR * nblkN;
    const int wrp  = threadIdx.x >> 6;
    const int lane = threadIdx.x & 63;
    const int row  = bloc * 4 + wrp;

    const float* X = isR ? Rmat : Nmat;
    unsigned short* Xsw = isR ? Rsw : Nsw;

    float2 v = *(const float2*)(X + (size_t)row * 128 + lane * 2);
    float s = fmaf(v.x, v.x, v.y * v.y);
    unsigned hbits = f32_to_bf16(v.x) | (f32_to_bf16(v.y) << 16);

    int boff = (lane * 4) ^ ((row & 7) << 4);
    *(unsigned*)((char*)Xsw + (size_t)row * 256 + boff) = hbits;

    #pragma unroll
    for (int o = 32; o > 0; o >>= 1) s += __shfl_down(s, o);

    if (lane == 0) {
        float e = __expf(-GAMMA * s);
        if (!isR) ENw[row] = W[row] * e;
        else      ER[row]  = e;
    }
}

// One block = 128x128 tile, 256 threads (4 waves 2x2), wave tile 64x64.
// LDS 64KB (A 32KB | B 32KB) -> 2 blocks/CU. Exact 8256-block 1D grid:
// [0,2080) mode0 tri, [2080,4160) mode1 tri, [4160,8256) mode2 full.
// Last-done block computes the final scalar (fused finalize).
__global__ __launch_bounds__(256, 2) void mmd_mfma_kernel(
    const unsigned short* __restrict__ Nsw, const unsigned short* __restrict__ Rsw,
    const float* __restrict__ ENw, const float* __restrict__ ER,
    const float* __restrict__ W,
    double* __restrict__ acc3, unsigned* __restrict__ counter,
    float* __restrict__ out)
{
    // ---- unrank ----
    int mode, bi, bj;
    {
        int bid = blockIdx.x;
        if (bid < 2 * SYM2) {
            mode = (bid >= SYM2) ? 1 : 0;
            int t = bid - mode * SYM2;
            int i = (int)(64.5f - sqrtf(4160.25f - 2.0f * (float)t));
            if (i < 0) i = 0;
            while ((i + 1) * NP2 - ((i + 1) * i) / 2 <= t) ++i;
            while (i * NP2 - (i * (i - 1)) / 2 > t) --i;
            bi = i;
            bj = i + (t - (i * NP2 - (i * (i - 1)) / 2));
        } else {
            mode = 2;
            int t = bid - 2 * SYM2;
            bi = t >> 6;
            bj = t & 63;
        }
    }

    const unsigned short *A, *B; const float *EA, *EB;
    if (mode == 0)      { A = Nsw; B = Nsw; EA = ENw; EB = ENw; }
    else if (mode == 1) { A = Rsw; B = Rsw; EA = ER;  EB = ER;  }
    else                { A = Nsw; B = Rsw; EA = ENw; EB = ER;  }

    const float scale = (mode < 2 && bj > bi) ? 2.0f : 1.0f;
    const bool diagblk = (mode < 2 && bi == bj);

    __shared__ __align__(16) char lds[65536];
    __shared__ double red[4];
    __shared__ int is_last;

    const int tid  = threadIdx.x;
    const int lane = tid & 63;
    const int wv   = tid >> 6;      // 0..3

    const char* gA = (const char*)A + ((size_t)bi << 15);
    const char* gB = (const char*)B + ((size_t)bj << 15);

    // ---- stage 64KB: linear gload_lds (global image pre-swizzled) ----
    #pragma unroll
    for (int it = 0; it < 8; ++it) {
        int c = (wv * 8 + it) * 1024;
        gload_lds16(gA + c + lane * 16, lds + c);
        gload_lds16(gB + c + lane * 16, lds + 32768 + c);
    }
    __syncthreads();

    const int wm = wv >> 1;          // 0..1 : 64-row half
    const int wn = wv & 1;           // 0..1 : 64-col half
    const int lg = lane >> 4;        // 0..3
    const int lr = lane & 15;
    const int swz = (lr & 7) << 4;

    f32x4 acc[4][4];
    #pragma unroll
    for (int mi = 0; mi < 4; ++mi)
        #pragma unroll
        for (int nj = 0; nj < 4; ++nj) acc[mi][nj] = (f32x4){0.f,0.f,0.f,0.f};

    #pragma unroll
    for (int ks = 0; ks < 4; ++ks) {
        const int koff = (ks * 64 + lg * 16) ^ swz;
        bf16x8 af[4], bfr[4];
        #pragma unroll
        for (int mi = 0; mi < 4; ++mi) {
            int r = wm * 64 + mi * 16 + lr;
            af[mi] = *(const bf16x8*)(lds + r * 256 + koff);
        }
        #pragma unroll
        for (int nj = 0; nj < 4; ++nj) {
            int r = wn * 64 + nj * 16 + lr;
            bfr[nj] = *(const bf16x8*)(lds + 32768 + r * 256 + koff);
        }
        __builtin_amdgcn_s_setprio(1);
        #pragma unroll
        for (int mi = 0; mi < 4; ++mi)
            #pragma unroll
            for (int nj = 0; nj < 4; ++nj)
                acc[mi][nj] = __builtin_amdgcn_mfma_f32_16x16x32_bf16(
                    af[mi], bfr[nj], acc[mi][nj], 0, 0, 0);
        __builtin_amdgcn_s_setprio(0);
    }

    // ---- epilogue: sum_ij EA_i*EB_j*exp(2g*g_ij), diag zeroed ----
    float eb[4];
    #pragma unroll
    for (int nj = 0; nj < 4; ++nj) eb[nj] = EB[bj * 128 + wn * 64 + nj * 16 + lr];

    float part = 0.f;
    if (!diagblk) {
        #pragma unroll
        for (int mi = 0; mi < 4; ++mi) {
            float4 ea4 = *(const float4*)&EA[bi * 128 + wm * 64 + mi * 16 + lg * 4];
            #pragma unroll
            for (int r = 0; r < 4; ++r) {
                float rowsum = 0.f;
                #pragma unroll
                for (int nj = 0; nj < 4; ++nj)
                    rowsum = fmaf(eb[nj], __expf(2.0f * GAMMA * acc[mi][nj][r]), rowsum);
                part = fmaf(((const float*)&ea4)[r], rowsum, part);
            }
        }
    } else {
        #pragma unroll
        for (int mi = 0; mi < 4; ++mi) {
            float4 ea4 = *(const float4*)&EA[bi * 128 + wm * 64 + mi * 16 + lg * 4];
            #pragma unroll
            for (int r = 0; r < 4; ++r) {
                int ci = wm * 64 + mi * 16 + lg * 4 + r;
                float rowsum = 0.f;
                #pragma unroll
                for (int nj = 0; nj < 4; ++nj) {
                    float e = __expf(2.0f * GAMMA * acc[mi][nj][r]);
                    if (ci == wn * 64 + nj * 16 + lr) e = 0.f;
                    rowsum = fmaf(eb[nj], e, rowsum);
                }
                part = fmaf(((const float*)&ea4)[r], rowsum, part);
            }
        }
    }
    part *= scale;

    double dp = (double)part;
    #pragma unroll
    for (int o = 32; o > 0; o >>= 1) dp += __shfl_down(dp, o);
    if (lane == 0) red[wv] = dp;
    __syncthreads();
    if (tid == 0) {
        atomicAdd(&acc3[mode], red[0] + red[1] + red[2] + red[3]);
        __threadfence();
        unsigned old = atomicAdd(counter, 1u);
        is_last = (old == NBLK - 1) ? 1 : 0;
    }
    __syncthreads();

    // ---- fused finalize: last-done block ----
    if (is_last) {
        double s = 0.0, s2 = 0.0;
        for (int i = tid; i < 8192; i += 256) {
            double w = (double)W[i];
            s += w; s2 += w * w;
        }
        double* redS  = (double*)lds;           // reuse LDS (compute done)
        double* redS2 = (double*)lds + 256;
        redS[tid] = s; redS2[tid] = s2;
        __syncthreads();
        for (int stride = 128; stride > 0; stride >>= 1) {
            if (tid < stride) {
                redS[tid]  += redS[tid + stride];
                redS2[tid] += redS2[tid + stride];
            }
            __syncthreads();
        }
        if (tid == 0) {
            double S = redS[0], S2 = redS2[0];
            // device-scope atomic reads (XCD-safe)
            double xxo = atomicAdd(&acc3[0], 0.0);
            double yyo = atomicAdd(&acc3[1], 0.0);
            double xyv = atomicAdd(&acc3[2], 0.0);
            double M = 8192.0;
            double xx = (xxo + S2) / (S * S);
            double yy = (yyo + M) / (M * M);
            double xy = xyv / (S * M);
            out[0] = (float)sqrt(fmax(xx + yy - 2.0 * xy, 0.0));
        }
    }
}

extern "C" void kernel_launch(void* const* d_in, const int* in_sizes, int n_in,
                              void* d_out, int out_size, void* d_ws, size_t ws_size,
                              hipStream_t stream) {
    const float* Nmat = (const float*)d_in[0];
    const float* Rmat = (const float*)d_in[1];
    const float* W    = (const float*)d_in[2];
    float* out = (float*)d_out;

    const int n = in_sizes[2];            // 8192
    const int d = in_sizes[0] / n;        // 128
    const int m = in_sizes[1] / d;        // 8192

    double* acc         = (double*)d_ws;
    unsigned* counter   = (unsigned*)((char*)d_ws + 64);
    float* ENw          = (float*)((char*)d_ws + 1024);
    float* ER           = (float*)((char*)d_ws + 33792);
    unsigned short* Nsw = (unsigned short*)((char*)d_ws + 66560);
    unsigned short* Rsw = (unsigned short*)((char*)d_ws + 66560 + 2097152);

    prep_kernel<<<(n + m) / 4, 256, 0, stream>>>(Nmat, Rmat, W, ENw, ER, Nsw, Rsw,
                                                 (unsigned*)d_ws, n / 4);

    mmd_mfma_kernel<<<NBLK, 256, 0, stream>>>(Nsw, Rsw, ENw, ER, W, acc, counter, out);
}

// Round 14
// 139.269 us; speedup vs baseline: 1.7468x; 1.7468x over previous
//
#include <hip/hip_runtime.h>
#include <hip/hip_bf16.h>
#include <math.h>

#define GAMMA 0.05f
#define NP2 64          // 8192/128 panels
#define SYM2 2080       // NP2*(NP2+1)/2
#define NBLK 8256       // 2*SYM2 + NP2*NP2

typedef __attribute__((ext_vector_type(8))) short bf16x8;
typedef __attribute__((ext_vector_type(4))) float f32x4;

static __device__ __forceinline__ unsigned f32_to_bf16(float x) {
    unsigned u = __float_as_uint(x);
    u += 0x7fffu + ((u >> 16) & 1u);   // RNE
    return u >> 16;
}

static __device__ __forceinline__ void gload_lds16(const void* g, void* l) {
    __builtin_amdgcn_global_load_lds(
        (const __attribute__((address_space(1))) void*)g,
        (__attribute__((address_space(3))) void*)l, 16, 0, 0);
}

// ws layout (bytes):
//   0       : double partials[8256]  (66048 B; every slot written, no init)
//   66560   : float ENw[8192] = W[i]*exp(-g*||N_i||^2)
//   99328   : float ER [8192] =      exp(-g*||R_i||^2)
//   132096  : bf16 Nsw[8192][128], row-major 256B rows, intra-row swizzle
//   2229248 : bf16 Rsw same
// Intra-row swizzle: byte ^= (row&7)<<4 -> conflict-free ds_read_b128 when
// 16 lanes read 16 consecutive rows at one 16B column.

__global__ __launch_bounds__(256) void prep_kernel(
    const float* __restrict__ Nmat, const float* __restrict__ Rmat,
    const float* __restrict__ W,
    float* __restrict__ ENw, float* __restrict__ ER,
    unsigned short* __restrict__ Nsw, unsigned short* __restrict__ Rsw,
    int nblkN)
{
    const int isR  = (blockIdx.x >= nblkN) ? 1 : 0;
    const int bloc = blockIdx.x - isR * nblkN;
    const int wrp  = threadIdx.x >> 6;
    const int lane = threadIdx.x & 63;
    const int row  = bloc * 4 + wrp;

    const float* X = isR ? Rmat : Nmat;
    unsigned short* Xsw = isR ? Rsw : Nsw;

    float2 v = *(const float2*)(X + (size_t)row * 128 + lane * 2);
    float s = fmaf(v.x, v.x, v.y * v.y);
    unsigned hbits = f32_to_bf16(v.x) | (f32_to_bf16(v.y) << 16);

    int boff = (lane * 4) ^ ((row & 7) << 4);
    *(unsigned*)((char*)Xsw + (size_t)row * 256 + boff) = hbits;

    #pragma unroll
    for (int o = 32; o > 0; o >>= 1) s += __shfl_down(s, o);

    if (lane == 0) {
        float e = __expf(-GAMMA * s);
        if (!isR) ENw[row] = W[row] * e;
        else      ER[row]  = e;
    }
}

// One block = 128x128 tile, 256 threads (4 waves 2x2), wave tile 64x64.
// LDS 64KB (A 32KB | B 32KB) -> 2 blocks/CU. Exact 8256-block 1D grid:
// [0,2080) mode0 tri, [2080,4160) mode1 tri, [4160,8256) mode2 full.
// Each block stores its f64 partial to partials[bid]; NO atomics, NO fence.
__global__ __launch_bounds__(256, 2) void mmd_mfma_kernel(
    const unsigned short* __restrict__ Nsw, const unsigned short* __restrict__ Rsw,
    const float* __restrict__ ENw, const float* __restrict__ ER,
    double* __restrict__ partials)
{
    // ---- unrank ----
    int mode, bi, bj;
    {
        int bid = blockIdx.x;
        if (bid < 2 * SYM2) {
            mode = (bid >= SYM2) ? 1 : 0;
            int t = bid - mode * SYM2;
            int i = (int)(64.5f - sqrtf(4160.25f - 2.0f * (float)t));
            if (i < 0) i = 0;
            while ((i + 1) * NP2 - ((i + 1) * i) / 2 <= t) ++i;
            while (i * NP2 - (i * (i - 1)) / 2 > t) --i;
            bi = i;
            bj = i + (t - (i * NP2 - (i * (i - 1)) / 2));
        } else {
            mode = 2;
            int t = bid - 2 * SYM2;
            bi = t >> 6;
            bj = t & 63;
        }
    }

    const unsigned short *A, *B; const float *EA, *EB;
    if (mode == 0)      { A = Nsw; B = Nsw; EA = ENw; EB = ENw; }
    else if (mode == 1) { A = Rsw; B = Rsw; EA = ER;  EB = ER;  }
    else                { A = Nsw; B = Rsw; EA = ENw; EB = ER;  }

    const float scale = (mode < 2 && bj > bi) ? 2.0f : 1.0f;
    const bool diagblk = (mode < 2 && bi == bj);

    __shared__ __align__(16) char lds[65536];
    __shared__ float red[4];

    const int tid  = threadIdx.x;
    const int lane = tid & 63;
    const int wv   = tid >> 6;      // 0..3

    const char* gA = (const char*)A + ((size_t)bi << 15);
    const char* gB = (const char*)B + ((size_t)bj << 15);

    // ---- stage 64KB: linear gload_lds (global image pre-swizzled) ----
    #pragma unroll
    for (int it = 0; it < 8; ++it) {
        int c = (wv * 8 + it) * 1024;
        gload_lds16(gA + c + lane * 16, lds + c);
        gload_lds16(gB + c + lane * 16, lds + 32768 + c);
    }
    __syncthreads();

    const int wm = wv >> 1;          // 0..1 : 64-row half
    const int wn = wv & 1;           // 0..1 : 64-col half
    const int lg = lane >> 4;        // 0..3
    const int lr = lane & 15;
    const int swz = (lr & 7) << 4;

    f32x4 acc[4][4];
    #pragma unroll
    for (int mi = 0; mi < 4; ++mi)
        #pragma unroll
        for (int nj = 0; nj < 4; ++nj) acc[mi][nj] = (f32x4){0.f,0.f,0.f,0.f};

    #pragma unroll
    for (int ks = 0; ks < 4; ++ks) {
        const int koff = (ks * 64 + lg * 16) ^ swz;
        bf16x8 af[4], bfr[4];
        #pragma unroll
        for (int mi = 0; mi < 4; ++mi) {
            int r = wm * 64 + mi * 16 + lr;
            af[mi] = *(const bf16x8*)(lds + r * 256 + koff);
        }
        #pragma unroll
        for (int nj = 0; nj < 4; ++nj) {
            int r = wn * 64 + nj * 16 + lr;
            bfr[nj] = *(const bf16x8*)(lds + 32768 + r * 256 + koff);
        }
        __builtin_amdgcn_s_setprio(1);
        #pragma unroll
        for (int mi = 0; mi < 4; ++mi)
            #pragma unroll
            for (int nj = 0; nj < 4; ++nj)
                acc[mi][nj] = __builtin_amdgcn_mfma_f32_16x16x32_bf16(
                    af[mi], bfr[nj], acc[mi][nj], 0, 0, 0);
        __builtin_amdgcn_s_setprio(0);
    }

    // ---- epilogue: sum_ij EA_i*EB_j*exp(2g*g_ij), diag zeroed ----
    float eb[4];
    #pragma unroll
    for (int nj = 0; nj < 4; ++nj) eb[nj] = EB[bj * 128 + wn * 64 + nj * 16 + lr];

    float part = 0.f;
    if (!diagblk) {
        #pragma unroll
        for (int mi = 0; mi < 4; ++mi) {
            float4 ea4 = *(const float4*)&EA[bi * 128 + wm * 64 + mi * 16 + lg * 4];
            #pragma unroll
            for (int r = 0; r < 4; ++r) {
                float rowsum = 0.f;
                #pragma unroll
                for (int nj = 0; nj < 4; ++nj)
                    rowsum = fmaf(eb[nj], __expf(2.0f * GAMMA * acc[mi][nj][r]), rowsum);
                part = fmaf(((const float*)&ea4)[r], rowsum, part);
            }
        }
    } else {
        #pragma unroll
        for (int mi = 0; mi < 4; ++mi) {
            float4 ea4 = *(const float4*)&EA[bi * 128 + wm * 64 + mi * 16 + lg * 4];
            #pragma unroll
            for (int r = 0; r < 4; ++r) {
                int ci = wm * 64 + mi * 16 + lg * 4 + r;
                float rowsum = 0.f;
                #pragma unroll
                for (int nj = 0; nj < 4; ++nj) {
                    float e = __expf(2.0f * GAMMA * acc[mi][nj][r]);
                    if (ci == wn * 64 + nj * 16 + lr) e = 0.f;
                    rowsum = fmaf(eb[nj], e, rowsum);
                }
                part = fmaf(((const float*)&ea4)[r], rowsum, part);
            }
        }
    }
    part *= scale;

    // wave reduce (f32, ample precision for <=16384 bounded terms)
    #pragma unroll
    for (int o = 32; o > 0; o >>= 1) part += __shfl_down(part, o);
    if (lane == 0) red[wv] = part;
    __syncthreads();
    if (tid == 0)
        partials[blockIdx.x] = (double)red[0] + (double)red[1]
                             + (double)red[2] + (double)red[3];
}

__global__ __launch_bounds__(256) void finalize_kernel(
    const float* __restrict__ W, const double* __restrict__ partials,
    float* __restrict__ out, int n, int m)
{
    __shared__ double r0[256], r1[256], r2[256], r3[256], r4[256];
    double xx = 0.0, yy = 0.0, xy = 0.0, s = 0.0, s2 = 0.0;
    const int tid = threadIdx.x;
    for (int i = tid; i < NBLK; i += 256) {
        double p = partials[i];
        if (i < SYM2)            xx += p;
        else if (i < 2 * SYM2)   yy += p;
        else                     xy += p;
    }
    for (int i = tid; i < n; i += 256) {
        double w = (double)W[i];
        s += w; s2 += w * w;
    }
    r0[tid] = xx; r1[tid] = yy; r2[tid] = xy; r3[tid] = s; r4[tid] = s2;
    __syncthreads();
    for (int stride = 128; stride > 0; stride >>= 1) {
        if (tid < stride) {
            r0[tid] += r0[tid + stride];
            r1[tid] += r1[tid + stride];
            r2[tid] += r2[tid + stride];
            r3[tid] += r3[tid + stride];
            r4[tid] += r4[tid + stride];
        }
        __syncthreads();
    }
    if (tid == 0) {
        double S = r3[0], S2 = r4[0], M = (double)m;
        double xxv = (r0[0] + S2) / (S * S);
        double yyv = (r1[0] + M) / (M * M);
        double xyv = r2[0] / (S * M);
        out[0] = (float)sqrt(fmax(xxv + yyv - 2.0 * xyv, 0.0));
    }
}

extern "C" void kernel_launch(void* const* d_in, const int* in_sizes, int n_in,
                              void* d_out, int out_size, void* d_ws, size_t ws_size,
                              hipStream_t stream) {
    const float* Nmat = (const float*)d_in[0];
    const float* Rmat = (const float*)d_in[1];
    const float* W    = (const float*)d_in[2];
    float* out = (float*)d_out;

    const int n = in_sizes[2];            // 8192
    const int d = in_sizes[0] / n;        // 128
    const int m = in_sizes[1] / d;        // 8192

    double* partials    = (double*)d_ws;
    float* ENw          = (float*)((char*)d_ws + 66560);
    float* ER           = (float*)((char*)d_ws + 99328);
    unsigned short* Nsw = (unsigned short*)((char*)d_ws + 132096);
    unsigned short* Rsw = (unsigned short*)((char*)d_ws + 2229248);

    prep_kernel<<<(n + m) / 4, 256, 0, stream>>>(Nmat, Rmat, W, ENw, ER, Nsw, Rsw, n / 4);

    mmd_mfma_kernel<<<NBLK, 256, 0, stream>>>(Nsw, Rsw, ENw, ER, partials);

    finalize_kernel<<<1, 256, 0, stream>>>(W, partials, out, n, m);
}